// Round 5
// baseline (451.621 us; speedup 1.0000x reference)
//
#include <hip/hip_runtime.h>
#include <stdint.h>

typedef short bf16x8 __attribute__((ext_vector_type(8)));
typedef float f32x4 __attribute__((ext_vector_type(4)));

#define NEG (-10000.0f)
#define LOG2E 1.44269504089f
#define LN2 0.69314718056f
#define EXP2F(x) __builtin_amdgcn_exp2f(x)
#define LOG2F(x) __builtin_amdgcn_logf(x)
#define RCPF(x) __builtin_amdgcn_rcpf(x)
constexpr int T_LEN = 512;
constexpr int BATCH = 128;

__device__ __forceinline__ unsigned short f2bf(float f) {
    union { float f; unsigned u; } v; v.f = f;
    return (unsigned short)((v.u + 0x7FFFu + ((v.u >> 16) & 1u)) >> 16);
}
__device__ __forceinline__ float bf2f(unsigned short s) {
    union { unsigned u; float f; } v; v.u = (unsigned)s << 16; return v.f;
}
// single-op RNE f32->bf16 (low 16 of v_cvt_pk_bf16_f32), identical rounding to f2bf
__device__ __forceinline__ unsigned short f2bf_fast(float f) {
    unsigned r;
    asm("v_cvt_pk_bf16_f32 %0, %1, %2" : "=v"(r) : "v"(f), "v"(f));
    return (unsigned short)r;
}
// true v_readlane broadcast (SGPR result, no LDS) — __shfl lowers to ds_bpermute, this doesn't
__device__ __forceinline__ float rlanef(float x, int l) {
    union { float f; int i; } a, r;
    a.f = x;
    r.i = __builtin_amdgcn_readlane(a.i, l);
    return r.f;
}
__device__ __forceinline__ f32x4 mfma16(bf16x8 a, bf16x8 b, f32x4 c) {
    return __builtin_amdgcn_mfma_f32_16x16x32_bf16(a, b, c, 0, 0, 0);
}

// ---------------- 1) embedding gather + bf16 convert: xt[b][t][64] ----------------
__global__ void __launch_bounds__(256) k_embed(const int* __restrict__ sent,
                                               const float* __restrict__ emb,
                                               unsigned short* __restrict__ xt) {
    int gid = blockIdx.x * 256 + threadIdx.x;
    int row = gid >> 5;                            // b*T + t
    int p   = gid & 31;
    int w = sent[row];
    float2 v = *(const float2*)(emb + (size_t)w * 64 + p * 2);
    unsigned o;
    asm("v_cvt_pk_bf16_f32 %0, %1, %2" : "=v"(o) : "v"(v.x), "v"(v.y));
    ((unsigned*)xt)[(size_t)row * 32 + p] = o;
}

// ---------------- 2) BiLSTM: 1 chain/block; x@Wih chunked into LDS ----------------
// Serial-latency-bound. This round: Whh MFMA restructured as TWO 2-deep chains
// per gate (8 live accumulators = +32 VGPRs; round-2's 16-acc/+64-VGPR split
// made the compiler serialize — success indicator is VGPR_Count rising ~150).
// h-reads issue before the zv read (zv consumed only post-MFMA).
__global__ void __launch_bounds__(512, 2) k_lstm(
        const unsigned short* __restrict__ xt,     // (B,T,64) bf16
        const float* __restrict__ Wih_f, const float* __restrict__ Whh_f, const float* __restrict__ b_f,
        const float* __restrict__ Wih_b, const float* __restrict__ Whh_b, const float* __restrict__ b_b,
        unsigned short* __restrict__ hbuf) {       // (B,T,256) bf16: [h_f | h_b]
    const int tid  = threadIdx.x;
    const int lane = tid & 63;
    const int w    = tid >> 6;            // wave 0..7: unit slice [16w,16w+16)
    const int b    = blockIdx.x & 127;
    const int dir  = blockIdx.x >> 7;

    const float* Wih  = dir ? Wih_b : Wih_f;
    const float* Whh  = dir ? Whh_b : Whh_f;
    const float* bias = dir ? b_b   : b_f;

    __shared__ __align__(16) unsigned short zbuf[2][32][512];  // [buf][t][u*4+g] 64KB
    __shared__ __align__(16) unsigned short hl[2][128];        // h ping-pong

    const int nlo = lane & 15;
    const int kg  = lane >> 4;
    const int u   = 16 * w + nlo;         // hidden unit owned by this lane

    // ---- Whh B-frags: 4 gates x 4 k-tiles, prescaled, resident ----
    bf16x8 hfrag[4][4];
    #pragma unroll
    for (int g = 0; g < 4; ++g) {
        const float sc = (g == 2) ? (-2.0f * LOG2E) : (-LOG2E);
        const int j = 128 * g + u;
        #pragma unroll
        for (int kt = 0; kt < 4; ++kt) {
            const float* src = Whh + (size_t)j * 128 + 32 * kt + kg * 8;
            bf16x8 tmp;
            #pragma unroll
            for (int q = 0; q < 8; ++q) tmp[q] = (short)f2bf(src[q] * sc);
            hfrag[g][kt] = tmp;
        }
    }
    // ---- Wih B-frags for zx phase: wave's n-span [64w,64w+64): 4 n-tiles x 2 k ----
    bf16x8 wx[4][2];
    float bsc[4];
    #pragma unroll
    for (int nt = 0; nt < 4; ++nt) {
        const int n = 64 * w + 16 * nt + nlo;
        const float scn = ((n >> 7) == 2) ? (-2.0f * LOG2E) : (-LOG2E);
        bsc[nt] = bias[n] * scn;
        #pragma unroll
        for (int kt = 0; kt < 2; ++kt) {
            const float* src = Wih + (size_t)n * 64 + 32 * kt + kg * 8;
            bf16x8 tmp;
            #pragma unroll
            for (int q = 0; q < 8; ++q) tmp[q] = (short)f2bf(src[q] * scn);
            wx[nt][kt] = tmp;
        }
    }

    const unsigned short* xb = xt + (size_t)b * T_LEN * 64;

    // x A-frags for chunk c: rows m=16rt+nlo <-> step 32c+m (time-reversed if dir)
    auto load_x = [&](int c, bf16x8 xf[2][2]) {
        const int tb = dir ? (511 - 32 * c) : (32 * c);
        #pragma unroll
        for (int rt = 0; rt < 2; ++rt) {
            const int m = 16 * rt + nlo;
            const int t = dir ? (tb - m) : (tb + m);
            xf[rt][0] = *(const bf16x8*)(xb + t * 64 + kg * 8);
            xf[rt][1] = *(const bf16x8*)(xb + t * 64 + 32 + kg * 8);
        }
    };
    // dense zx burst: 16 MFMA/wave covering 32 steps x 64 n-cols
    auto zx_phase = [&](int buf, bf16x8 xf[2][2]) {
        #pragma unroll
        for (int rt = 0; rt < 2; ++rt) {
            #pragma unroll
            for (int nt = 0; nt < 4; ++nt) {
                f32x4 a = (f32x4){bsc[nt], bsc[nt], bsc[nt], bsc[nt]};
                a = mfma16(xf[rt][0], wx[nt][0], a);
                a = mfma16(xf[rt][1], wx[nt][1], a);
                const int n = 64 * w + 16 * nt + nlo;
                const int base = (n & 127) * 4 + (n >> 7);   // [u*4+g] packing
                #pragma unroll
                for (int r = 0; r < 4; ++r)
                    zbuf[buf][16 * rt + 4 * kg + r][base] = f2bf(a[r]);
            }
        }
    };

    if (tid < 128) { hl[0][tid] = 0; hl[1][tid] = 0; }
    bf16x8 xfA[2][2], xfB[2][2];
    load_x(0, xfA);
    zx_phase(0, xfA);
    load_x(1, xfB);
    __syncthreads();

    float c = 0.0f;                        // cell state (kg-redundant, lockstep)
    const f32x4 z4 = (f32x4){0.f, 0.f, 0.f, 0.f};   // loop-invariant MFMA C-in
    // pointer-march for the h global store (replaces per-step select+mul+add64)
    unsigned short* hbp = hbuf + ((size_t)b * T_LEN + (dir ? 511 : 0)) * 256 + dir * 128 + u;
    const ptrdiff_t hstep = dir ? -256 : 256;

    for (int ch = 0; ch < 16; ++ch) {
        const int p = ch & 1;
        if (ch + 1 < 16) zx_phase(1 - p, p ? xfA : xfB);   // next chunk's zx
        if (ch + 2 < 16) load_x(ch + 2, p ? xfB : xfA);    // prefetch chunk+2 x

        #pragma unroll 2
        for (int s = 0; s < 32; ++s) {
            const int hp = (32 * ch + s) & 1;

            const unsigned short* hr = hl[hp];
            bf16x8 h0 = *(const bf16x8*)(hr      + kg * 8);   // critical-path reads first
            bf16x8 h1 = *(const bf16x8*)(hr + 32 + kg * 8);
            bf16x8 h2 = *(const bf16x8*)(hr + 64 + kg * 8);
            bf16x8 h3 = *(const bf16x8*)(hr + 96 + kg * 8);
            ushort4 zv = *(const ushort4*)(&zbuf[p][s][u * 4]);   // consumed post-MFMA

            // two 2-deep chains per gate (A: kt0->kt1, B: kt2->kt3)
            f32x4 aiA = mfma16(h0, hfrag[0][0], z4);
            f32x4 afA = mfma16(h0, hfrag[1][0], z4);
            f32x4 agA = mfma16(h0, hfrag[2][0], z4);
            f32x4 aoA = mfma16(h0, hfrag[3][0], z4);
            f32x4 aiB = mfma16(h2, hfrag[0][2], z4);
            f32x4 afB = mfma16(h2, hfrag[1][2], z4);
            f32x4 agB = mfma16(h2, hfrag[2][2], z4);
            f32x4 aoB = mfma16(h2, hfrag[3][2], z4);
            aiA = mfma16(h1, hfrag[0][1], aiA);
            afA = mfma16(h1, hfrag[1][1], afA);
            agA = mfma16(h1, hfrag[2][1], agA);
            aoA = mfma16(h1, hfrag[3][1], aoA);
            aiB = mfma16(h3, hfrag[0][3], aiB);
            afB = mfma16(h3, hfrag[1][3], afB);
            agB = mfma16(h3, hfrag[2][3], agB);
            aoB = mfma16(h3, hfrag[3][3], aoB);

            float zi = (bf2f(zv.x) + aiA[0]) + aiB[0];
            float zf = (bf2f(zv.y) + afA[0]) + afB[0];
            float zg = (bf2f(zv.z) + agA[0]) + agB[0];
            float zo = (bf2f(zv.w) + aoA[0]) + aoB[0];

            float ig = RCPF(1.0f + EXP2F(zi));              // acc = -log2e*z
            float fg = RCPF(1.0f + EXP2F(zf));
            float tg = 2.0f * RCPF(1.0f + EXP2F(zg)) - 1.0f; // acc = -2log2e*z
            float og = RCPF(1.0f + EXP2F(zo));
            c = fg * c + ig * tg;
            float tc = 2.0f * RCPF(1.0f + EXP2F(-2.0f * LOG2E * c)) - 1.0f;
            unsigned short hv = f2bf_fast(og * tc);

            if (kg == 0) {
                hl[1 - hp][u] = hv;                            // next step's A operand
                *hbp = hv;                                     // fire-and-forget
            }
            hbp += hstep;
            // raw barrier: drain LDS ops only, not global stores / x prefetch
            __asm__ volatile("" ::: "memory");
            __builtin_amdgcn_s_waitcnt(0xc07f);
            __builtin_amdgcn_s_barrier();
            __asm__ volatile("" ::: "memory");
        }
    }
}

// ---------------- 3) feats = [h_f|h_b] @ W_out^T + b_out  (BT x 32) ----------------
__global__ void __launch_bounds__(256) k_feats(const unsigned short* __restrict__ hbuf,
                                               const float* __restrict__ Wout,
                                               const float* __restrict__ bout,
                                               float* __restrict__ feats) {
    const int lane = threadIdx.x & 63;
    const int wv   = blockIdx.x * 4 + (threadIdx.x >> 6);
    const int nlo  = lane & 15, kg = lane >> 4;

    bf16x8 bw[2][8];
    #pragma unroll
    for (int nt = 0; nt < 2; ++nt) {
        const float* src0 = Wout + (size_t)(nt * 16 + nlo) * 256 + kg * 8;
        #pragma unroll
        for (int kt = 0; kt < 8; ++kt) {
            bf16x8 tmp;
            #pragma unroll
            for (int q = 0; q < 8; ++q) tmp[q] = (short)f2bf(src0[kt * 32 + q]);
            bw[nt][kt] = tmp;
        }
    }
    float bb0 = bout[nlo], bb1 = bout[16 + nlo];

    for (int rg = 0; rg < 4; ++rg) {
        int row0 = wv * 64 + rg * 16;
        f32x4 a0 = {0.f,0.f,0.f,0.f}, a1 = {0.f,0.f,0.f,0.f};
        #pragma unroll
        for (int kt = 0; kt < 8; ++kt) {
            bf16x8 a = *(const bf16x8*)(hbuf + (size_t)(row0 + nlo) * 256 + kt * 32 + kg * 8);
            a0 = mfma16(a, bw[0][kt], a0);
            a1 = mfma16(a, bw[1][kt], a1);
        }
        #pragma unroll
        for (int r = 0; r < 4; ++r) {
            size_t rr = (size_t)(row0 + kg * 4 + r) * 32;
            feats[rr + nlo]      = a0[r] + bb0;
            feats[rr + 16 + nlo] = a1[r] + bb1;
        }
    }
}

// ---------------- 4) CRF forward + gold: one wave per batch, fv in registers ----------------
// Factorized recurrence with v_readlane gathers (round-4, verified). This round:
// DEPTH-8 register prefetch of the emit column. The per-step fb load was only
// depth-2 covered (~340cy) vs L2-miss/HBM latency (~450-900cy) -> ~100us of
// stall. Blocks of 8 steps: issue 8 independent loads (N[8]) at block top,
// consume L[8] from the previous block. Fully unrolled -> stays in registers.
__global__ void __launch_bounds__(64) k_crf(const float* __restrict__ feats,
                                            const float* __restrict__ trans,
                                            const int* __restrict__ tags,
                                            float* __restrict__ out) {
    const int b    = blockIdx.x;
    const int lane = threadIdx.x;
    const int k1   = lane & 31;

    __shared__ float str[1024];
    for (int i = lane; i < 1024; i += 64) str[i] = trans[i];

    // full exp-domain transition row for this lane's target state k1
    float E[32];
    float sumE = 0.0f;
    #pragma unroll
    for (int j = 0; j < 32; ++j) {
        E[j] = EXP2F(trans[k1 * 32 + j] * LOG2E);   // NEG entries -> exactly 0
        sumE += E[j];
    }
    __syncthreads();

    // gold score
    const int* tg = tags + (size_t)b * T_LEN;
    const float* fb = feats + (size_t)b * T_LEN * 32;
    float gsum = 0.0f;
    for (int t = lane; t < T_LEN; t += 64) {
        int cur = tg[t];
        int prev = t ? tg[t - 1] : 0;
        gsum += str[cur * 32 + prev] + fb[(size_t)t * 32 + cur];
    }
    #pragma unroll
    for (int o = 32; o >= 1; o >>= 1) gsum += __shfl_xor(gsum, o);

    // ---- t = 0 closed form: p0 = 1 (j=0 NEG-cancel) + sumE (E[0]==0) ----
    float coff = NEG * LOG2E;
    float fv2  = coff + LOG2F(1.0f + sumE) + fb[k1] * LOG2E;
    coff = rlanef(fv2, 16);                 // v_readlane: bulk-lane level proxy

    // ---- t = 1..511 in blocks of 8 with a named register ring ----
    float L[8];
    #pragma unroll
    for (int i = 0; i < 8; ++i) L[i] = fb[(size_t)(1 + i) * 32 + k1];

    for (int t0 = 1; t0 < T_LEN; t0 += 8) {
        float N[8];
        #pragma unroll
        for (int i = 0; i < 8; ++i) {           // issue 8 loads for block t0+8 early
            const int tn = t0 + 8 + i;
            N[i] = (tn < T_LEN) ? fb[(size_t)tn * 32 + k1] : 0.0f;
        }
        #pragma unroll
        for (int i = 0; i < 8; ++i) {
            if (t0 + i < T_LEN) {
                float u = EXP2F(fv2 - coff);    // bounded: coff is 1-step-stale level
                float p0 = 0.f, p1 = 0.f, p2 = 0.f, p3 = 0.f;
                #pragma unroll
                for (int j = 0; j < 32; j += 4) {
                    p0 += E[j]     * rlanef(u, j);      // v_fmac vdst, sgpr, vgpr
                    p1 += E[j + 1] * rlanef(u, j + 1);
                    p2 += E[j + 2] * rlanef(u, j + 2);
                    p3 += E[j + 3] * rlanef(u, j + 3);
                }
                float p = (p0 + p1) + (p2 + p3);
                p = fmaxf(p, 1e-37f);          // dead-state (k1=0) underflow guard
                fv2  = coff + LOG2F(p) + L[i] * LOG2E;
                coff = rlanef(fv2, 16);        // v_readlane
            }
        }
        #pragma unroll
        for (int i = 0; i < 8; ++i) L[i] = N[i];
    }

    float v2 = fv2 + str[k1] * LOG2E;
    float m2 = v2;
    #pragma unroll
    for (int o = 32; o >= 1; o >>= 1) m2 = fmaxf(m2, __shfl_xor(m2, o));
    float e = EXP2F(v2 - m2);
    #pragma unroll
    for (int o = 32; o >= 1; o >>= 1) e += __shfl_xor(e, o);
    float logZ = LN2 * (m2 + LOG2F(e) - 1.0f);   // -1: each k counted twice

    if (lane == 0) {
        float gold = gsum + str[tg[T_LEN - 1]];
        atomicAdd(out, logZ - gold);
    }
}

extern "C" void kernel_launch(void* const* d_in, const int* in_sizes, int n_in,
                              void* d_out, int out_size, void* d_ws, size_t ws_size,
                              hipStream_t stream) {
    const int*   sent  = (const int*)d_in[0];
    const int*   tags  = (const int*)d_in[1];
    const float* emb   = (const float*)d_in[2];
    const float* Wih_f = (const float*)d_in[3];
    const float* Whh_f = (const float*)d_in[4];
    const float* b_f   = (const float*)d_in[5];
    const float* Wih_b = (const float*)d_in[6];
    const float* Whh_b = (const float*)d_in[7];
    const float* b_b   = (const float*)d_in[8];
    const float* Wout  = (const float*)d_in[9];
    const float* bout  = (const float*)d_in[10];
    const float* trans = (const float*)d_in[11];
    (void)in_sizes; (void)n_in; (void)ws_size;

    char* ws = (char*)d_ws;
    unsigned short* hbuf  = (unsigned short*)ws;                         // 33,554,432 B
    float*          feats = (float*)(ws + 33554432);                     //  8,388,608 B
    unsigned short* xt    = (unsigned short*)(ws + 33554432 + 8388608);  //  8,388,608 B

    (void)hipMemsetAsync(d_out, 0, sizeof(float) * out_size, stream);
    k_embed<<<8192, 256, 0, stream>>>(sent, emb, xt);
    k_lstm <<<256,  512, 0, stream>>>(xt, Wih_f, Whh_f, b_f, Wih_b, Whh_b, b_b, hbuf);
    k_feats<<<256,  256, 0, stream>>>(hbuf, Wout, bout, feats);
    k_crf  <<<BATCH, 64, 0, stream>>>(feats, trans, tags, (float*)d_out);
}

// Round 6
// 447.954 us; speedup vs baseline: 1.0082x; 1.0082x over previous
//
#include <hip/hip_runtime.h>
#include <stdint.h>

typedef short bf16x8 __attribute__((ext_vector_type(8)));
typedef float f32x4 __attribute__((ext_vector_type(4)));

#define NEG (-10000.0f)
#define LOG2E 1.44269504089f
#define LN2 0.69314718056f
#define EXP2F(x) __builtin_amdgcn_exp2f(x)
#define LOG2F(x) __builtin_amdgcn_logf(x)
#define RCPF(x) __builtin_amdgcn_rcpf(x)
constexpr int T_LEN = 512;
constexpr int BATCH = 128;

__device__ __forceinline__ unsigned short f2bf(float f) {
    union { float f; unsigned u; } v; v.f = f;
    return (unsigned short)((v.u + 0x7FFFu + ((v.u >> 16) & 1u)) >> 16);
}
__device__ __forceinline__ float bf2f(unsigned short s) {
    union { unsigned u; float f; } v; v.u = (unsigned)s << 16; return v.f;
}
// single-op RNE f32->bf16 (low 16 of v_cvt_pk_bf16_f32), identical rounding to f2bf
__device__ __forceinline__ unsigned short f2bf_fast(float f) {
    unsigned r;
    asm("v_cvt_pk_bf16_f32 %0, %1, %2" : "=v"(r) : "v"(f), "v"(f));
    return (unsigned short)r;
}
// pack 8 consecutive f32 -> bf16x8 via 4x v_cvt_pk_bf16_f32 (RNE, == old k_embed path)
__device__ __forceinline__ bf16x8 cvt8(const float* p) {
    float4 a = *(const float4*)p;
    float4 b = *(const float4*)(p + 4);
    union { unsigned u[4]; bf16x8 v; } r;
    asm("v_cvt_pk_bf16_f32 %0, %1, %2" : "=v"(r.u[0]) : "v"(a.x), "v"(a.y));
    asm("v_cvt_pk_bf16_f32 %0, %1, %2" : "=v"(r.u[1]) : "v"(a.z), "v"(a.w));
    asm("v_cvt_pk_bf16_f32 %0, %1, %2" : "=v"(r.u[2]) : "v"(b.x), "v"(b.y));
    asm("v_cvt_pk_bf16_f32 %0, %1, %2" : "=v"(r.u[3]) : "v"(b.z), "v"(b.w));
    return r.v;
}
// true v_readlane broadcast (SGPR result, no LDS) — __shfl lowers to ds_bpermute, this doesn't
__device__ __forceinline__ float rlanef(float x, int l) {
    union { float f; int i; } a, r;
    a.f = x;
    r.i = __builtin_amdgcn_readlane(a.i, l);
    return r.f;
}
__device__ __forceinline__ f32x4 mfma16(bf16x8 a, bf16x8 b, f32x4 c) {
    return __builtin_amdgcn_mfma_f32_16x16x32_bf16(a, b, c, 0, 0, 0);
}

// ---------------- 1) BiLSTM (round-4 serial body) with FUSED embedding gather ----------------
// Serial-latency-bound: 1 block/CU, 8 waves barrier-locked per step. The serial
// loop is the verified 286us round-4 form (chained 4-deep MFMA from zero-C).
// NEW: load_x gathers emb[sent[t]] + cvt_pk directly (k_embed kernel and the
// 33MB xt round-trip eliminated). The sent->emb indirection sits 2 chunks
// (~64 steps) ahead of consumption — latency fully covered.
__global__ void __launch_bounds__(512, 2) k_lstm(
        const int* __restrict__ sent,              // (B,T) word ids
        const float* __restrict__ emb,             // (V,64) f32
        const float* __restrict__ Wih_f, const float* __restrict__ Whh_f, const float* __restrict__ b_f,
        const float* __restrict__ Wih_b, const float* __restrict__ Whh_b, const float* __restrict__ b_b,
        unsigned short* __restrict__ hbuf) {       // (B,T,256) bf16: [h_f | h_b]
    const int tid  = threadIdx.x;
    const int lane = tid & 63;
    const int w    = tid >> 6;            // wave 0..7: unit slice [16w,16w+16)
    const int b    = blockIdx.x & 127;
    const int dir  = blockIdx.x >> 7;

    const float* Wih  = dir ? Wih_b : Wih_f;
    const float* Whh  = dir ? Whh_b : Whh_f;
    const float* bias = dir ? b_b   : b_f;

    __shared__ __align__(16) unsigned short zbuf[2][32][512];  // [buf][t][u*4+g] 64KB
    __shared__ __align__(16) unsigned short hl[2][128];        // h ping-pong

    const int nlo = lane & 15;
    const int kg  = lane >> 4;
    const int u   = 16 * w + nlo;         // hidden unit owned by this lane

    // ---- Whh B-frags: 4 gates x 4 k-tiles, prescaled, resident ----
    bf16x8 hfrag[4][4];
    #pragma unroll
    for (int g = 0; g < 4; ++g) {
        const float sc = (g == 2) ? (-2.0f * LOG2E) : (-LOG2E);
        const int j = 128 * g + u;
        #pragma unroll
        for (int kt = 0; kt < 4; ++kt) {
            const float* src = Whh + (size_t)j * 128 + 32 * kt + kg * 8;
            bf16x8 tmp;
            #pragma unroll
            for (int q = 0; q < 8; ++q) tmp[q] = (short)f2bf(src[q] * sc);
            hfrag[g][kt] = tmp;
        }
    }
    // ---- Wih B-frags for zx phase: wave's n-span [64w,64w+64): 4 n-tiles x 2 k ----
    bf16x8 wx[4][2];
    float bsc[4];
    #pragma unroll
    for (int nt = 0; nt < 4; ++nt) {
        const int n = 64 * w + 16 * nt + nlo;
        const float scn = ((n >> 7) == 2) ? (-2.0f * LOG2E) : (-LOG2E);
        bsc[nt] = bias[n] * scn;
        #pragma unroll
        for (int kt = 0; kt < 2; ++kt) {
            const float* src = Wih + (size_t)n * 64 + 32 * kt + kg * 8;
            bf16x8 tmp;
            #pragma unroll
            for (int q = 0; q < 8; ++q) tmp[q] = (short)f2bf(src[q] * scn);
            wx[nt][kt] = tmp;
        }
    }

    const int* sb = sent + (size_t)b * T_LEN;

    // x A-frags for chunk c: rows m=16rt+nlo <-> step 32c+m (time-reversed if dir)
    // FUSED gather: sent[t] -> emb row -> cvt_pk to bf16 (replaces xt read)
    auto load_x = [&](int c, bf16x8 xf[2][2]) {
        const int tb = dir ? (511 - 32 * c) : (32 * c);
        #pragma unroll
        for (int rt = 0; rt < 2; ++rt) {
            const int m = 16 * rt + nlo;
            const int t = dir ? (tb - m) : (tb + m);
            const float* er = emb + (size_t)sb[t] * 64;
            xf[rt][0] = cvt8(er + kg * 8);
            xf[rt][1] = cvt8(er + 32 + kg * 8);
        }
    };
    // dense zx burst: 16 MFMA/wave covering 32 steps x 64 n-cols
    auto zx_phase = [&](int buf, bf16x8 xf[2][2]) {
        #pragma unroll
        for (int rt = 0; rt < 2; ++rt) {
            #pragma unroll
            for (int nt = 0; nt < 4; ++nt) {
                f32x4 a = (f32x4){bsc[nt], bsc[nt], bsc[nt], bsc[nt]};
                a = mfma16(xf[rt][0], wx[nt][0], a);
                a = mfma16(xf[rt][1], wx[nt][1], a);
                const int n = 64 * w + 16 * nt + nlo;
                const int base = (n & 127) * 4 + (n >> 7);   // [u*4+g] packing
                #pragma unroll
                for (int r = 0; r < 4; ++r)
                    zbuf[buf][16 * rt + 4 * kg + r][base] = f2bf(a[r]);
            }
        }
    };

    if (tid < 128) { hl[0][tid] = 0; hl[1][tid] = 0; }
    bf16x8 xfA[2][2], xfB[2][2];
    load_x(0, xfA);
    zx_phase(0, xfA);
    load_x(1, xfB);
    __syncthreads();

    float c = 0.0f;                        // cell state (kg-redundant, lockstep)
    const f32x4 z4 = (f32x4){0.f, 0.f, 0.f, 0.f};   // loop-invariant MFMA C-in
    // pointer-march for the h global store (replaces per-step select+mul+add64)
    unsigned short* hbp = hbuf + ((size_t)b * T_LEN + (dir ? 511 : 0)) * 256 + dir * 128 + u;
    const ptrdiff_t hstep = dir ? -256 : 256;

    for (int ch = 0; ch < 16; ++ch) {
        const int p = ch & 1;
        if (ch + 1 < 16) zx_phase(1 - p, p ? xfA : xfB);   // next chunk's zx
        if (ch + 2 < 16) load_x(ch + 2, p ? xfB : xfA);    // prefetch chunk+2 x

        #pragma unroll 2
        for (int s = 0; s < 32; ++s) {
            const int hp = (32 * ch + s) & 1;

            ushort4 zv = *(const ushort4*)(&zbuf[p][s][u * 4]);   // 4 gates' zx
            const unsigned short* hr = hl[hp];
            bf16x8 h0 = *(const bf16x8*)(hr      + kg * 8);
            bf16x8 h1 = *(const bf16x8*)(hr + 32 + kg * 8);
            bf16x8 h2 = *(const bf16x8*)(hr + 64 + kg * 8);
            bf16x8 h3 = *(const bf16x8*)(hr + 96 + kg * 8);

            // MFMAs start from the shared zero quad (no per-step splat movs);
            // zx is folded in after, on the single consumed scalar.
            f32x4 ai = mfma16(h0, hfrag[0][0], z4);
            f32x4 af = mfma16(h0, hfrag[1][0], z4);
            f32x4 ag = mfma16(h0, hfrag[2][0], z4);
            f32x4 ao = mfma16(h0, hfrag[3][0], z4);
            #pragma unroll
            for (int kt = 1; kt < 4; ++kt) {
                bf16x8 hh = (kt == 1) ? h1 : (kt == 2) ? h2 : h3;
                ai = mfma16(hh, hfrag[0][kt], ai);
                af = mfma16(hh, hfrag[1][kt], af);
                ag = mfma16(hh, hfrag[2][kt], ag);
                ao = mfma16(hh, hfrag[3][kt], ao);
            }

            float zi = bf2f(zv.x), zf = bf2f(zv.y), zg = bf2f(zv.z), zo = bf2f(zv.w);
            float ig = RCPF(1.0f + EXP2F(ai[0] + zi));              // acc = -log2e*z
            float fg = RCPF(1.0f + EXP2F(af[0] + zf));
            float tg = 2.0f * RCPF(1.0f + EXP2F(ag[0] + zg)) - 1.0f; // acc = -2log2e*z
            float og = RCPF(1.0f + EXP2F(ao[0] + zo));
            c = fg * c + ig * tg;
            float tc = 2.0f * RCPF(1.0f + EXP2F(-2.0f * LOG2E * c)) - 1.0f;
            unsigned short hv = f2bf_fast(og * tc);

            if (kg == 0) {
                hl[1 - hp][u] = hv;                            // next step's A operand
                *hbp = hv;                                     // fire-and-forget
            }
            hbp += hstep;
            // raw barrier: drain LDS ops only, not global stores / x prefetch
            __asm__ volatile("" ::: "memory");
            __builtin_amdgcn_s_waitcnt(0xc07f);
            __builtin_amdgcn_s_barrier();
            __asm__ volatile("" ::: "memory");
        }
    }
}

// ---------------- 2) feats = [h_f|h_b] @ W_out^T + b_out  (BT x 32) ----------------
__global__ void __launch_bounds__(256) k_feats(const unsigned short* __restrict__ hbuf,
                                               const float* __restrict__ Wout,
                                               const float* __restrict__ bout,
                                               float* __restrict__ feats) {
    const int lane = threadIdx.x & 63;
    const int wv   = blockIdx.x * 4 + (threadIdx.x >> 6);
    const int nlo  = lane & 15, kg = lane >> 4;

    bf16x8 bw[2][8];
    #pragma unroll
    for (int nt = 0; nt < 2; ++nt) {
        const float* src0 = Wout + (size_t)(nt * 16 + nlo) * 256 + kg * 8;
        #pragma unroll
        for (int kt = 0; kt < 8; ++kt) {
            bf16x8 tmp;
            #pragma unroll
            for (int q = 0; q < 8; ++q) tmp[q] = (short)f2bf(src0[kt * 32 + q]);
            bw[nt][kt] = tmp;
        }
    }
    float bb0 = bout[nlo], bb1 = bout[16 + nlo];

    for (int rg = 0; rg < 4; ++rg) {
        int row0 = wv * 64 + rg * 16;
        f32x4 a0 = {0.f,0.f,0.f,0.f}, a1 = {0.f,0.f,0.f,0.f};
        #pragma unroll
        for (int kt = 0; kt < 8; ++kt) {
            bf16x8 a = *(const bf16x8*)(hbuf + (size_t)(row0 + nlo) * 256 + kt * 32 + kg * 8);
            a0 = mfma16(a, bw[0][kt], a0);
            a1 = mfma16(a, bw[1][kt], a1);
        }
        #pragma unroll
        for (int r = 0; r < 4; ++r) {
            size_t rr = (size_t)(row0 + kg * 4 + r) * 32;
            feats[rr + nlo]      = a0[r] + bb0;
            feats[rr + 16 + nlo] = a1[r] + bb1;
        }
    }
}

// ---------------- 3) CRF forward + gold: one wave per batch, fv in registers ----------------
// Factorized recurrence with v_readlane gathers + depth-8 register prefetch
// (round-5 form, kept unchanged this round for clean residual attribution).
__global__ void __launch_bounds__(64) k_crf(const float* __restrict__ feats,
                                            const float* __restrict__ trans,
                                            const int* __restrict__ tags,
                                            float* __restrict__ out) {
    const int b    = blockIdx.x;
    const int lane = threadIdx.x;
    const int k1   = lane & 31;

    __shared__ float str[1024];
    for (int i = lane; i < 1024; i += 64) str[i] = trans[i];

    // full exp-domain transition row for this lane's target state k1
    float E[32];
    float sumE = 0.0f;
    #pragma unroll
    for (int j = 0; j < 32; ++j) {
        E[j] = EXP2F(trans[k1 * 32 + j] * LOG2E);   // NEG entries -> exactly 0
        sumE += E[j];
    }
    __syncthreads();

    // gold score
    const int* tg = tags + (size_t)b * T_LEN;
    const float* fb = feats + (size_t)b * T_LEN * 32;
    float gsum = 0.0f;
    for (int t = lane; t < T_LEN; t += 64) {
        int cur = tg[t];
        int prev = t ? tg[t - 1] : 0;
        gsum += str[cur * 32 + prev] + fb[(size_t)t * 32 + cur];
    }
    #pragma unroll
    for (int o = 32; o >= 1; o >>= 1) gsum += __shfl_xor(gsum, o);

    // ---- t = 0 closed form: p0 = 1 (j=0 NEG-cancel) + sumE (E[0]==0) ----
    float coff = NEG * LOG2E;
    float fv2  = coff + LOG2F(1.0f + sumE) + fb[k1] * LOG2E;
    coff = rlanef(fv2, 16);                 // v_readlane: bulk-lane level proxy

    // ---- t = 1..511 in blocks of 8 with a named register ring ----
    float L[8];
    #pragma unroll
    for (int i = 0; i < 8; ++i) L[i] = fb[(size_t)(1 + i) * 32 + k1];

    for (int t0 = 1; t0 < T_LEN; t0 += 8) {
        float N[8];
        #pragma unroll
        for (int i = 0; i < 8; ++i) {           // issue 8 loads for block t0+8 early
            const int tn = t0 + 8 + i;
            N[i] = (tn < T_LEN) ? fb[(size_t)tn * 32 + k1] : 0.0f;
        }
        #pragma unroll
        for (int i = 0; i < 8; ++i) {
            if (t0 + i < T_LEN) {
                float u = EXP2F(fv2 - coff);    // bounded: coff is 1-step-stale level
                float p0 = 0.f, p1 = 0.f, p2 = 0.f, p3 = 0.f;
                #pragma unroll
                for (int j = 0; j < 32; j += 4) {
                    p0 += E[j]     * rlanef(u, j);      // v_fmac vdst, sgpr, vgpr
                    p1 += E[j + 1] * rlanef(u, j + 1);
                    p2 += E[j + 2] * rlanef(u, j + 2);
                    p3 += E[j + 3] * rlanef(u, j + 3);
                }
                float p = (p0 + p1) + (p2 + p3);
                p = fmaxf(p, 1e-37f);          // dead-state (k1=0) underflow guard
                fv2  = coff + LOG2F(p) + L[i] * LOG2E;
                coff = rlanef(fv2, 16);        // v_readlane
            }
        }
        #pragma unroll
        for (int i = 0; i < 8; ++i) L[i] = N[i];
    }

    float v2 = fv2 + str[k1] * LOG2E;
    float m2 = v2;
    #pragma unroll
    for (int o = 32; o >= 1; o >>= 1) m2 = fmaxf(m2, __shfl_xor(m2, o));
    float e = EXP2F(v2 - m2);
    #pragma unroll
    for (int o = 32; o >= 1; o >>= 1) e += __shfl_xor(e, o);
    float logZ = LN2 * (m2 + LOG2F(e) - 1.0f);   // -1: each k counted twice

    if (lane == 0) {
        float gold = gsum + str[tg[T_LEN - 1]];
        atomicAdd(out, logZ - gold);
    }
}

extern "C" void kernel_launch(void* const* d_in, const int* in_sizes, int n_in,
                              void* d_out, int out_size, void* d_ws, size_t ws_size,
                              hipStream_t stream) {
    const int*   sent  = (const int*)d_in[0];
    const int*   tags  = (const int*)d_in[1];
    const float* emb   = (const float*)d_in[2];
    const float* Wih_f = (const float*)d_in[3];
    const float* Whh_f = (const float*)d_in[4];
    const float* b_f   = (const float*)d_in[5];
    const float* Wih_b = (const float*)d_in[6];
    const float* Whh_b = (const float*)d_in[7];
    const float* b_b   = (const float*)d_in[8];
    const float* Wout  = (const float*)d_in[9];
    const float* bout  = (const float*)d_in[10];
    const float* trans = (const float*)d_in[11];
    (void)in_sizes; (void)n_in; (void)ws_size;

    char* ws = (char*)d_ws;
    unsigned short* hbuf  = (unsigned short*)ws;                         // 33,554,432 B
    float*          feats = (float*)(ws + 33554432);                     //  8,388,608 B

    (void)hipMemsetAsync(d_out, 0, sizeof(float) * out_size, stream);
    k_lstm <<<256,  512, 0, stream>>>(sent, emb, Wih_f, Whh_f, b_f, Wih_b, Whh_b, b_b, hbuf);
    k_feats<<<256,  256, 0, stream>>>(hbuf, Wout, bout, feats);
    k_crf  <<<BATCH, 64, 0, stream>>>(feats, trans, tags, (float*)d_out);
}

// Round 7
// 431.670 us; speedup vs baseline: 1.0462x; 1.0377x over previous
//
#include <hip/hip_runtime.h>
#include <stdint.h>

typedef short bf16x8 __attribute__((ext_vector_type(8)));
typedef float f32x4 __attribute__((ext_vector_type(4)));

#define NEG (-10000.0f)
#define LOG2E 1.44269504089f
#define LN2 0.69314718056f
#define EXP2F(x) __builtin_amdgcn_exp2f(x)
#define LOG2F(x) __builtin_amdgcn_logf(x)
#define RCPF(x) __builtin_amdgcn_rcpf(x)
constexpr int T_LEN = 512;
constexpr int BATCH = 128;

__device__ __forceinline__ unsigned short f2bf(float f) {
    union { float f; unsigned u; } v; v.f = f;
    return (unsigned short)((v.u + 0x7FFFu + ((v.u >> 16) & 1u)) >> 16);
}
__device__ __forceinline__ float bf2f(unsigned short s) {
    union { unsigned u; float f; } v; v.u = (unsigned)s << 16; return v.f;
}
// single-op RNE f32->bf16 (low 16 of v_cvt_pk_bf16_f32), identical rounding to f2bf
__device__ __forceinline__ unsigned short f2bf_fast(float f) {
    unsigned r;
    asm("v_cvt_pk_bf16_f32 %0, %1, %2" : "=v"(r) : "v"(f), "v"(f));
    return (unsigned short)r;
}
// true v_readlane broadcast (SGPR result, no LDS) — __shfl lowers to ds_bpermute, this doesn't
__device__ __forceinline__ float rlanef(float x, int l) {
    union { float f; int i; } a, r;
    a.f = x;
    r.i = __builtin_amdgcn_readlane(a.i, l);
    return r.f;
}
// cross-half sum: returns (x.lo_half + x.hi_half) in EVERY lane, via one
// v_permlane32_swap_b32. With both operands = x the result pair is
// {dup(x.lo), dup(x.hi)} under either direction convention, so a+b is
// direction-proof — no lane select needed.
__device__ __forceinline__ float halfsum(float x) {
    float a = x, b = x;
    asm("v_permlane32_swap_b32 %0, %1" : "+v"(a), "+v"(b));
    return a + b;
}
__device__ __forceinline__ f32x4 mfma16(bf16x8 a, bf16x8 b, f32x4 c) {
    return __builtin_amdgcn_mfma_f32_16x16x32_bf16(a, b, c, 0, 0, 0);
}

// ---------------- 1) embedding gather + bf16 convert: xt[b][t][64] ----------------
__global__ void __launch_bounds__(256) k_embed(const int* __restrict__ sent,
                                               const float* __restrict__ emb,
                                               unsigned short* __restrict__ xt) {
    int gid = blockIdx.x * 256 + threadIdx.x;
    int row = gid >> 5;                            // b*T + t
    int p   = gid & 31;
    int w = sent[row];
    float2 v = *(const float2*)(emb + (size_t)w * 64 + p * 2);
    unsigned o;
    asm("v_cvt_pk_bf16_f32 %0, %1, %2" : "=v"(o) : "v"(v.x), "v"(v.y));
    ((unsigned*)xt)[(size_t)row * 32 + p] = o;
}

// ---------------- 2) BiLSTM (round-4 verified 286us form, byte-identical) ----------------
// 1 chain/block, 8 waves barrier-locked. zx = sc*(Wih·x+b) precomputed per
// 32-step chunk into LDS (double-buffered). Serial loop: 5 LDS reads, 16
// chained MFMA from zero-C, exp2-only gates, lgkm-only barrier. Fused embed
// gather REGRESSED (+18us, round 6): extra VALU in the serial region competes
// with the critical chain — keep staging via xt.
__global__ void __launch_bounds__(512, 2) k_lstm(
        const unsigned short* __restrict__ xt,     // (B,T,64) bf16
        const float* __restrict__ Wih_f, const float* __restrict__ Whh_f, const float* __restrict__ b_f,
        const float* __restrict__ Wih_b, const float* __restrict__ Whh_b, const float* __restrict__ b_b,
        unsigned short* __restrict__ hbuf) {       // (B,T,256) bf16: [h_f | h_b]
    const int tid  = threadIdx.x;
    const int lane = tid & 63;
    const int w    = tid >> 6;            // wave 0..7: unit slice [16w,16w+16)
    const int b    = blockIdx.x & 127;
    const int dir  = blockIdx.x >> 7;

    const float* Wih  = dir ? Wih_b : Wih_f;
    const float* Whh  = dir ? Whh_b : Whh_f;
    const float* bias = dir ? b_b   : b_f;

    __shared__ __align__(16) unsigned short zbuf[2][32][512];  // [buf][t][u*4+g] 64KB
    __shared__ __align__(16) unsigned short hl[2][128];        // h ping-pong

    const int nlo = lane & 15;
    const int kg  = lane >> 4;
    const int u   = 16 * w + nlo;         // hidden unit owned by this lane

    // ---- Whh B-frags: 4 gates x 4 k-tiles, prescaled, resident ----
    bf16x8 hfrag[4][4];
    #pragma unroll
    for (int g = 0; g < 4; ++g) {
        const float sc = (g == 2) ? (-2.0f * LOG2E) : (-LOG2E);
        const int j = 128 * g + u;
        #pragma unroll
        for (int kt = 0; kt < 4; ++kt) {
            const float* src = Whh + (size_t)j * 128 + 32 * kt + kg * 8;
            bf16x8 tmp;
            #pragma unroll
            for (int q = 0; q < 8; ++q) tmp[q] = (short)f2bf(src[q] * sc);
            hfrag[g][kt] = tmp;
        }
    }
    // ---- Wih B-frags for zx phase: wave's n-span [64w,64w+64): 4 n-tiles x 2 k ----
    bf16x8 wx[4][2];
    float bsc[4];
    #pragma unroll
    for (int nt = 0; nt < 4; ++nt) {
        const int n = 64 * w + 16 * nt + nlo;
        const float scn = ((n >> 7) == 2) ? (-2.0f * LOG2E) : (-LOG2E);
        bsc[nt] = bias[n] * scn;
        #pragma unroll
        for (int kt = 0; kt < 2; ++kt) {
            const float* src = Wih + (size_t)n * 64 + 32 * kt + kg * 8;
            bf16x8 tmp;
            #pragma unroll
            for (int q = 0; q < 8; ++q) tmp[q] = (short)f2bf(src[q] * scn);
            wx[nt][kt] = tmp;
        }
    }

    const unsigned short* xb = xt + (size_t)b * T_LEN * 64;

    // x A-frags for chunk c: rows m=16rt+nlo <-> step 32c+m (time-reversed if dir)
    auto load_x = [&](int c, bf16x8 xf[2][2]) {
        const int tb = dir ? (511 - 32 * c) : (32 * c);
        #pragma unroll
        for (int rt = 0; rt < 2; ++rt) {
            const int m = 16 * rt + nlo;
            const int t = dir ? (tb - m) : (tb + m);
            xf[rt][0] = *(const bf16x8*)(xb + t * 64 + kg * 8);
            xf[rt][1] = *(const bf16x8*)(xb + t * 64 + 32 + kg * 8);
        }
    };
    // dense zx burst: 16 MFMA/wave covering 32 steps x 64 n-cols
    auto zx_phase = [&](int buf, bf16x8 xf[2][2]) {
        #pragma unroll
        for (int rt = 0; rt < 2; ++rt) {
            #pragma unroll
            for (int nt = 0; nt < 4; ++nt) {
                f32x4 a = (f32x4){bsc[nt], bsc[nt], bsc[nt], bsc[nt]};
                a = mfma16(xf[rt][0], wx[nt][0], a);
                a = mfma16(xf[rt][1], wx[nt][1], a);
                const int n = 64 * w + 16 * nt + nlo;
                const int base = (n & 127) * 4 + (n >> 7);   // [u*4+g] packing
                #pragma unroll
                for (int r = 0; r < 4; ++r)
                    zbuf[buf][16 * rt + 4 * kg + r][base] = f2bf(a[r]);
            }
        }
    };

    if (tid < 128) { hl[0][tid] = 0; hl[1][tid] = 0; }
    bf16x8 xfA[2][2], xfB[2][2];
    load_x(0, xfA);
    zx_phase(0, xfA);
    load_x(1, xfB);
    __syncthreads();

    float c = 0.0f;                        // cell state (kg-redundant, lockstep)
    const f32x4 z4 = (f32x4){0.f, 0.f, 0.f, 0.f};   // loop-invariant MFMA C-in
    // pointer-march for the h global store (replaces per-step select+mul+add64)
    unsigned short* hbp = hbuf + ((size_t)b * T_LEN + (dir ? 511 : 0)) * 256 + dir * 128 + u;
    const ptrdiff_t hstep = dir ? -256 : 256;

    for (int ch = 0; ch < 16; ++ch) {
        const int p = ch & 1;
        if (ch + 1 < 16) zx_phase(1 - p, p ? xfA : xfB);   // next chunk's zx
        if (ch + 2 < 16) load_x(ch + 2, p ? xfB : xfA);    // prefetch chunk+2 x

        #pragma unroll 2
        for (int s = 0; s < 32; ++s) {
            const int hp = (32 * ch + s) & 1;

            ushort4 zv = *(const ushort4*)(&zbuf[p][s][u * 4]);   // 4 gates' zx
            const unsigned short* hr = hl[hp];
            bf16x8 h0 = *(const bf16x8*)(hr      + kg * 8);
            bf16x8 h1 = *(const bf16x8*)(hr + 32 + kg * 8);
            bf16x8 h2 = *(const bf16x8*)(hr + 64 + kg * 8);
            bf16x8 h3 = *(const bf16x8*)(hr + 96 + kg * 8);

            // MFMAs start from the shared zero quad (no per-step splat movs);
            // zx is folded in after, on the single consumed scalar.
            f32x4 ai = mfma16(h0, hfrag[0][0], z4);
            f32x4 af = mfma16(h0, hfrag[1][0], z4);
            f32x4 ag = mfma16(h0, hfrag[2][0], z4);
            f32x4 ao = mfma16(h0, hfrag[3][0], z4);
            #pragma unroll
            for (int kt = 1; kt < 4; ++kt) {
                bf16x8 hh = (kt == 1) ? h1 : (kt == 2) ? h2 : h3;
                ai = mfma16(hh, hfrag[0][kt], ai);
                af = mfma16(hh, hfrag[1][kt], af);
                ag = mfma16(hh, hfrag[2][kt], ag);
                ao = mfma16(hh, hfrag[3][kt], ao);
            }

            float zi = bf2f(zv.x), zf = bf2f(zv.y), zg = bf2f(zv.z), zo = bf2f(zv.w);
            float ig = RCPF(1.0f + EXP2F(ai[0] + zi));              // acc = -log2e*z
            float fg = RCPF(1.0f + EXP2F(af[0] + zf));
            float tg = 2.0f * RCPF(1.0f + EXP2F(ag[0] + zg)) - 1.0f; // acc = -2log2e*z
            float og = RCPF(1.0f + EXP2F(ao[0] + zo));
            c = fg * c + ig * tg;
            float tc = 2.0f * RCPF(1.0f + EXP2F(-2.0f * LOG2E * c)) - 1.0f;
            unsigned short hv = f2bf_fast(og * tc);

            if (kg == 0) {
                hl[1 - hp][u] = hv;                            // next step's A operand
                *hbp = hv;                                     // fire-and-forget
            }
            hbp += hstep;
            // raw barrier: drain LDS ops only, not global stores / x prefetch
            __asm__ volatile("" ::: "memory");
            __builtin_amdgcn_s_waitcnt(0xc07f);
            __builtin_amdgcn_s_barrier();
            __asm__ volatile("" ::: "memory");
        }
    }
}

// ---------------- 3) feats = [h_f|h_b] @ W_out^T + b_out  (BT x 32) ----------------
__global__ void __launch_bounds__(256) k_feats(const unsigned short* __restrict__ hbuf,
                                               const float* __restrict__ Wout,
                                               const float* __restrict__ bout,
                                               float* __restrict__ feats) {
    const int lane = threadIdx.x & 63;
    const int wv   = blockIdx.x * 4 + (threadIdx.x >> 6);
    const int nlo  = lane & 15, kg = lane >> 4;

    bf16x8 bw[2][8];
    #pragma unroll
    for (int nt = 0; nt < 2; ++nt) {
        const float* src0 = Wout + (size_t)(nt * 16 + nlo) * 256 + kg * 8;
        #pragma unroll
        for (int kt = 0; kt < 8; ++kt) {
            bf16x8 tmp;
            #pragma unroll
            for (int q = 0; q < 8; ++q) tmp[q] = (short)f2bf(src0[kt * 32 + q]);
            bw[nt][kt] = tmp;
        }
    }
    float bb0 = bout[nlo], bb1 = bout[16 + nlo];

    for (int rg = 0; rg < 4; ++rg) {
        int row0 = wv * 64 + rg * 16;
        f32x4 a0 = {0.f,0.f,0.f,0.f}, a1 = {0.f,0.f,0.f,0.f};
        #pragma unroll
        for (int kt = 0; kt < 8; ++kt) {
            bf16x8 a = *(const bf16x8*)(hbuf + (size_t)(row0 + nlo) * 256 + kt * 32 + kg * 8);
            a0 = mfma16(a, bw[0][kt], a0);
            a1 = mfma16(a, bw[1][kt], a1);
        }
        #pragma unroll
        for (int r = 0; r < 4; ++r) {
            size_t rr = (size_t)(row0 + kg * 4 + r) * 32;
            feats[rr + nlo]      = a0[r] + bb0;
            feats[rr + 16 + nlo] = a1[r] + bb1;
        }
    }
}

// ---------------- 4) CRF forward + gold: one wave per batch ----------------
// HALF-SPLIT factorized recurrence: lanes 32-63 previously duplicated lanes
// 0-31 exactly. Now half h = lane>>5 owns transition terms j === h (mod 2):
// 16 readlane+fmac pairs per lane instead of 32 (the v_readlane->SGPR->v_fmac
// hazard pairs were the dominant per-step cost, ~490cy/step measured). Halves
// combined with ONE v_permlane32_swap_b32 + add (direction-proof: with both
// operands = x the output pair is {dup(x.lo),dup(x.hi)} either way).
__global__ void __launch_bounds__(64) k_crf(const float* __restrict__ feats,
                                            const float* __restrict__ trans,
                                            const int* __restrict__ tags,
                                            float* __restrict__ out) {
    const int b    = blockIdx.x;
    const int lane = threadIdx.x;
    const int k1   = lane & 31;
    const int half = lane >> 5;

    __shared__ float str[1024];
    for (int i = lane; i < 1024; i += 64) str[i] = trans[i];

    // exp-domain transition row, parity-split: E[i] = exp(trans[k1][2i+half])
    float E[16];
    float sumE_h = 0.0f;
    #pragma unroll
    for (int i = 0; i < 16; ++i) {
        E[i] = EXP2F(trans[k1 * 32 + 2 * i + half] * LOG2E);   // NEG -> exactly 0
        sumE_h += E[i];
    }
    float sumE = halfsum(sumE_h);          // full-row sum, all lanes
    __syncthreads();

    // gold score
    const int* tg = tags + (size_t)b * T_LEN;
    const float* fb = feats + (size_t)b * T_LEN * 32;
    float gsum = 0.0f;
    for (int t = lane; t < T_LEN; t += 64) {
        int cur = tg[t];
        int prev = t ? tg[t - 1] : 0;
        gsum += str[cur * 32 + prev] + fb[(size_t)t * 32 + cur];
    }
    #pragma unroll
    for (int o = 32; o >= 1; o >>= 1) gsum += __shfl_xor(gsum, o);

    // ---- t = 0 closed form: p0 = 1 (j=0 NEG-cancel) + sumE (E[j=0]==0) ----
    float coff = NEG * LOG2E;
    float fv2  = coff + LOG2F(1.0f + sumE) + fb[k1] * LOG2E;
    coff = rlanef(fv2, 16);                 // v_readlane: bulk-lane level proxy

    // ---- t = 1..511 in blocks of 8 with a named register ring ----
    float L[8];
    #pragma unroll
    for (int i = 0; i < 8; ++i) L[i] = fb[(size_t)(1 + i) * 32 + k1];

    for (int t0 = 1; t0 < T_LEN; t0 += 8) {
        float N[8];
        #pragma unroll
        for (int i = 0; i < 8; ++i) {           // issue 8 loads for block t0+8 early
            const int tn = t0 + 8 + i;
            N[i] = (tn < T_LEN) ? fb[(size_t)tn * 32 + k1] : 0.0f;
        }
        #pragma unroll
        for (int i = 0; i < 8; ++i) {
            if (t0 + i < T_LEN) {
                float u = EXP2F(fv2 - coff);    // bounded: coff is 1-step-stale level
                // batch the 16 readlanes first (SGPR writes age before fmac reads)
                float s[16];
                #pragma unroll
                for (int j = 0; j < 16; ++j) s[j] = rlanef(u, 2 * j + half);
                float p0 = 0.f, p1 = 0.f, p2 = 0.f, p3 = 0.f;
                #pragma unroll
                for (int j = 0; j < 16; j += 4) {
                    p0 += E[j]     * s[j];
                    p1 += E[j + 1] * s[j + 1];
                    p2 += E[j + 2] * s[j + 2];
                    p3 += E[j + 3] * s[j + 3];
                }
                float ph = (p0 + p1) + (p2 + p3);   // this half's partial
                float p  = halfsum(ph);             // even+odd, all lanes
                p = fmaxf(p, 1e-37f);          // dead-state (k1=0) underflow guard
                fv2  = coff + LOG2F(p) + L[i] * LOG2E;
                coff = rlanef(fv2, 16);        // v_readlane
            }
        }
        #pragma unroll
        for (int i = 0; i < 8; ++i) L[i] = N[i];
    }

    float v2 = fv2 + str[k1] * LOG2E;
    float m2 = v2;
    #pragma unroll
    for (int o = 32; o >= 1; o >>= 1) m2 = fmaxf(m2, __shfl_xor(m2, o));
    float e = EXP2F(v2 - m2);
    #pragma unroll
    for (int o = 32; o >= 1; o >>= 1) e += __shfl_xor(e, o);
    float logZ = LN2 * (m2 + LOG2F(e) - 1.0f);   // -1: each k counted twice

    if (lane == 0) {
        float gold = gsum + str[tg[T_LEN - 1]];
        atomicAdd(out, logZ - gold);
    }
}

extern "C" void kernel_launch(void* const* d_in, const int* in_sizes, int n_in,
                              void* d_out, int out_size, void* d_ws, size_t ws_size,
                              hipStream_t stream) {
    const int*   sent  = (const int*)d_in[0];
    const int*   tags  = (const int*)d_in[1];
    const float* emb   = (const float*)d_in[2];
    const float* Wih_f = (const float*)d_in[3];
    const float* Whh_f = (const float*)d_in[4];
    const float* b_f   = (const float*)d_in[5];
    const float* Wih_b = (const float*)d_in[6];
    const float* Whh_b = (const float*)d_in[7];
    const float* b_b   = (const float*)d_in[8];
    const float* Wout  = (const float*)d_in[9];
    const float* bout  = (const float*)d_in[10];
    const float* trans = (const float*)d_in[11];
    (void)in_sizes; (void)n_in; (void)ws_size;

    char* ws = (char*)d_ws;
    unsigned short* hbuf  = (unsigned short*)ws;                         // 33,554,432 B
    float*          feats = (float*)(ws + 33554432);                     //  8,388,608 B
    unsigned short* xt    = (unsigned short*)(ws + 33554432 + 8388608);  //  8,388,608 B

    (void)hipMemsetAsync(d_out, 0, sizeof(float) * out_size, stream);
    k_embed<<<8192, 256, 0, stream>>>(sent, emb, xt);
    k_lstm <<<256,  512, 0, stream>>>(xt, Wih_f, Whh_f, b_f, Wih_b, Whh_b, b_b, hbuf);
    k_feats<<<256,  256, 0, stream>>>(hbuf, Wout, bout, feats);
    k_crf  <<<BATCH, 64, 0, stream>>>(feats, trans, tags, (float*)d_out);
}